// Round 4
// baseline (183.549 us; speedup 1.0000x reference)
//
#include <hip/hip_runtime.h>
#include <math.h>

#define NN 384
#define DD 2
#define TT 128
#define EE 256

// ---------------------------------------------------------------------------
// Layout helper: TR=true reads v transposed as [t][n][d] (coalesced float2),
// TR=false reads the original [n][d][t] layout (fallback when ws too small).
// ---------------------------------------------------------------------------
template <bool TR>
__device__ __forceinline__ float2 loadV(const float* __restrict__ v, int t, int n) {
    if (TR) {
        return *reinterpret_cast<const float2*>(v + ((size_t)t * NN + n) * DD);
    } else {
        return make_float2(v[(n * DD + 0) * TT + t], v[(n * DD + 1) * TT + t]);
    }
}

// ---------------------------------------------------------------------------
// Prep: transpose v0 (N,D,T) -> v0t (T,N,D), and zero the scalar output.
// grid = N*D*T/256 = 384 blocks exactly.
// ---------------------------------------------------------------------------
__global__ __launch_bounds__(256) void prep_tr(const float* __restrict__ v0,
                                               float* __restrict__ v0t,
                                               float* __restrict__ out) {
    int o = blockIdx.x * 256 + threadIdx.x;
    if (o == 0) out[0] = 0.0f;
    int t = o / (NN * DD);
    int r = o - t * (NN * DD);
    int n = r >> 1;
    int d = r & 1;
    v0t[o] = v0[(n * DD + d) * TT + t];
}

__global__ void zero_out(float* out) { out[0] = 0.0f; }

// ---------------------------------------------------------------------------
// Event intensity: E=256 events, one block. Recomputes the position prefix
// inline (exact cumsum order), exact idx_f / clamp / rem semantics.
// ---------------------------------------------------------------------------
template <bool TR>
__global__ __launch_bounds__(EE) void event_kernel(const float* __restrict__ data,
                                                   const float* __restrict__ z0,
                                                   const float* __restrict__ vsrc,
                                                   const float* __restrict__ beta,
                                                   const float* __restrict__ t0p,
                                                   const float* __restrict__ tnp,
                                                   float* __restrict__ out) {
    int e = threadIdx.x;
    float dt = (tnp[0] - t0p[0]) * (1.0f / TT);
    float fi = data[e * 3 + 0];
    float fj = data[e * 3 + 1];
    float tm = data[e * 3 + 2];
    int i = (int)floorf(fi);
    int j = (int)floorf(fj);
    float idx_f = floorf(tm / dt);
    float idx_cl = (idx_f < (float)TT) ? idx_f : (idx_f - 1.0f);
    int idx = (int)idx_cl;
    float rem = tm - idx_f * dt;   // NOTE: unclamped idx_f, as in reference

    const float2* z2 = reinterpret_cast<const float2*>(z0);
    float2 zi = z2[i];
    float2 zj = z2[j];
    for (int t = 0; t < idx; ++t) {
        float2 vi = loadV<TR>(vsrc, t, i);
        float2 vj = loadV<TR>(vsrc, t, j);
        zi.x = fmaf(vi.x, dt, zi.x); zi.y = fmaf(vi.y, dt, zi.y);
        zj.x = fmaf(vj.x, dt, zj.x); zj.y = fmaf(vj.y, dt, zj.y);
    }
    float2 vi = loadV<TR>(vsrc, idx, i);
    float2 vj = loadV<TR>(vsrc, idx, j);
    float Zi0 = fmaf(vi.x, rem, zi.x), Zi1 = fmaf(vi.y, rem, zi.y);
    float Zj0 = fmaf(vj.x, rem, zj.x), Zj1 = fmaf(vj.y, rem, zj.y);
    float d0 = Zi0 - Zj0, d1 = Zi1 - Zj1;
    float contrib = beta[idx] - (d0 * d0 + d1 * d1);

    #pragma unroll
    for (int off = 32; off > 0; off >>= 1) contrib += __shfl_xor(contrib, off, 64);
    if ((threadIdx.x & 63) == 0) atomicAdd(out, contrib);
}

// ---------------------------------------------------------------------------
// Non-event integral: thread per (i,j) cell of the full N x N grid, active
// only for i<j. i = tid/N is wave-uniform (384 % 64 == 0), so node-i loads
// broadcast; node-j loads are coalesced float2 in the transposed layout.
// Positions carried incrementally: z_{t+1} = z_t + v_t * dt.
// ---------------------------------------------------------------------------
template <bool TR>
__global__ __launch_bounds__(256) void pair_kernel(const float* __restrict__ vsrc,
                                                   const float* __restrict__ z0,
                                                   const float* __restrict__ beta,
                                                   const float* __restrict__ t0p,
                                                   const float* __restrict__ tnp,
                                                   float* __restrict__ out) {
    __shared__ float sbeta[TT];
    if (threadIdx.x < TT) sbeta[threadIdx.x] = beta[threadIdx.x];
    __syncthreads();

    int tid = blockIdx.x * 256 + threadIdx.x;
    int i = tid / NN;
    int j = tid - i * NN;

    float acc = 0.0f;
    if (j > i) {
        float dt = (tnp[0] - t0p[0]) * (1.0f / TT);
        const float2* z2 = reinterpret_cast<const float2*>(z0);
        float2 zi = z2[i];
        float2 zj = z2[j];
        const float sp_half = 0.8862269254527580f;  // sqrt(pi)/2

        #pragma unroll 4
        for (int t = 0; t < TT; ++t) {
            float2 vi = loadV<TR>(vsrc, t, i);
            float2 vj = loadV<TR>(vsrc, t, j);
            float dz0 = zi.x - zj.x, dz1 = zi.y - zj.y;
            float dv0 = vi.x - vj.x, dv1 = vi.y - vj.y;

            float a2 = fmaxf(fmaf(dv0, dv0, dv1 * dv1), 1e-12f);
            float inv_a = rsqrtf(a2);
            float a = a2 * inv_a;                    // sqrt(a2)
            float b = fmaf(dz0, dv0, dz1 * dv1);
            float u = b * inv_a;                     // a*c = b/a
            float m = fmaf(dz0, dz0, dz1 * dz1) - u * u;
            float ediff = erff(fmaf(a, dt, u)) - erff(u);
            acc = fmaf(__expf(sbeta[t] - m) * inv_a, sp_half * ediff, acc);

            zi.x = fmaf(vi.x, dt, zi.x); zi.y = fmaf(vi.y, dt, zi.y);
            zj.x = fmaf(vj.x, dt, zj.x); zj.y = fmaf(vj.y, dt, zj.y);
        }
    }

    #pragma unroll
    for (int off = 32; off > 0; off >>= 1) acc += __shfl_xor(acc, off, 64);
    if ((threadIdx.x & 63) == 0) atomicAdd(out, -acc);
}

// ---------------------------------------------------------------------------
extern "C" void kernel_launch(void* const* d_in, const int* in_sizes, int n_in,
                              void* d_out, int out_size, void* d_ws, size_t ws_size,
                              hipStream_t stream) {
    const float* data = (const float*)d_in[0];
    const float* t0p  = (const float*)d_in[1];
    const float* tnp  = (const float*)d_in[2];
    const float* z0   = (const float*)d_in[3];
    const float* v0   = (const float*)d_in[4];
    const float* beta = (const float*)d_in[5];
    float* out = (float*)d_out;
    float* v0t = (float*)d_ws;

    bool tr = ws_size >= sizeof(float) * (size_t)(NN * DD * TT);

    if (tr) {
        prep_tr<<<(NN * DD * TT) / 256, 256, 0, stream>>>(v0, v0t, out);
        event_kernel<true><<<1, EE, 0, stream>>>(data, z0, v0t, beta, t0p, tnp, out);
        pair_kernel<true><<<(NN * NN) / 256, 256, 0, stream>>>(v0t, z0, beta, t0p, tnp, out);
    } else {
        zero_out<<<1, 1, 0, stream>>>(out);
        event_kernel<false><<<1, EE, 0, stream>>>(data, z0, v0, beta, t0p, tnp, out);
        pair_kernel<false><<<(NN * NN) / 256, 256, 0, stream>>>(v0, z0, beta, t0p, tnp, out);
    }
}

// Round 5
// 106.939 us; speedup vs baseline: 1.7164x; 1.7164x over previous
//
#include <hip/hip_runtime.h>
#include <math.h>

#define NN 384
#define DD 2
#define TT 128
#define EE 256
#define CHUNKS 8
#define CLEN (TT / CHUNKS)            // 16 steps per chunk
#define PAIRBLOCKS ((NN * NN) / 256)  // 576
#define NPARTIAL (PAIRBLOCKS * CHUNKS)

// ws layout (floats): v0t [T][N][D] | Zs [T][N][D] | partials [NPARTIAL]
#define WS_V0T 0
#define WS_ZS (TT * NN * DD)
#define WS_PART (2 * TT * NN * DD)
#define WS_FLOATS (WS_PART + NPARTIAL)

// ---------------------------------------------------------------------------
// K1: transpose v0 (N,D,T)->(T,N,D), compute step-start positions Zs[t][n][d]
// (exact cumsum order), zero out[0]. Blocks 0..383 transpose, 384..386 prefix.
// ---------------------------------------------------------------------------
__global__ __launch_bounds__(256) void prep_kernel(const float* __restrict__ v0,
                                                   const float* __restrict__ z0,
                                                   const float* __restrict__ t0p,
                                                   const float* __restrict__ tnp,
                                                   float* __restrict__ ws,
                                                   float* __restrict__ out) {
    int bx = blockIdx.x;
    if (bx < 384) {
        int o = bx * 256 + threadIdx.x;           // o in [0, T*N*D)
        if (o == 0) out[0] = 0.0f;
        int t = o / (NN * DD);
        int r = o - t * (NN * DD);                // r = n*2+d
        ws[WS_V0T + o] = v0[r * TT + t];
    } else {
        int nd = (bx - 384) * 256 + threadIdx.x;  // [0, 768)
        if (nd < NN * DD) {
            float dt = (tnp[0] - t0p[0]) * (1.0f / TT);
            float z = z0[nd];
            for (int t = 0; t < TT; ++t) {
                ws[WS_ZS + t * (NN * DD) + nd] = z;   // coalesced per iteration
                z += v0[nd * TT + t] * dt;            // cumsum order
            }
        }
    }
}

// ---------------------------------------------------------------------------
// K2: pair chunks (blocks 0..NPARTIAL-1) + event block (block NPARTIAL).
// Pair block b: pb = b % 576 covers 256 (i,j) cells; c = b / 576 covers
// t in [c*CLEN, (c+1)*CLEN). Starts from precomputed Zs, carries z locally.
// Writes one partial per block (no same-address atomics on the hot path).
// ---------------------------------------------------------------------------
__global__ __launch_bounds__(256) void pair_event_kernel(const float* __restrict__ ws_ro,
                                                         const float* __restrict__ z0,
                                                         const float* __restrict__ beta,
                                                         const float* __restrict__ data,
                                                         const float* __restrict__ t0p,
                                                         const float* __restrict__ tnp,
                                                         float* __restrict__ partials,
                                                         float* __restrict__ out) {
    const float* v0t = ws_ro + WS_V0T;
    const float* Zs  = ws_ro + WS_ZS;
    int bx = blockIdx.x;

    if (bx == NPARTIAL) {
        // ---- event intensity: one block, one event per thread ----
        int e = threadIdx.x;
        float dt = (tnp[0] - t0p[0]) * (1.0f / TT);
        float fi = data[e * 3 + 0];
        float fj = data[e * 3 + 1];
        float tm = data[e * 3 + 2];
        int i = (int)floorf(fi);
        int j = (int)floorf(fj);
        float idx_f = floorf(tm / dt);
        float idx_cl = (idx_f < (float)TT) ? idx_f : (idx_f - 1.0f);
        int idx = (int)idx_cl;
        float rem = tm - idx_f * dt;              // unclamped idx_f, as in ref

        int bi = (idx * NN + i) * DD, bj = (idx * NN + j) * DD;
        float Zi0 = fmaf(v0t[bi + 0], rem, Zs[bi + 0]);
        float Zi1 = fmaf(v0t[bi + 1], rem, Zs[bi + 1]);
        float Zj0 = fmaf(v0t[bj + 0], rem, Zs[bj + 0]);
        float Zj1 = fmaf(v0t[bj + 1], rem, Zs[bj + 1]);
        float d0 = Zi0 - Zj0, d1 = Zi1 - Zj1;
        float contrib = beta[idx] - (d0 * d0 + d1 * d1);

        #pragma unroll
        for (int off = 32; off > 0; off >>= 1) contrib += __shfl_xor(contrib, off, 64);
        if ((threadIdx.x & 63) == 0) atomicAdd(out, contrib);
        return;
    }

    // ---- non-event integral chunk ----
    int pb = bx % PAIRBLOCKS;
    int c  = bx / PAIRBLOCKS;
    int t0 = c * CLEN;
    int tid = pb * 256 + threadIdx.x;
    int i = tid / NN;                              // wave-uniform (384 = 6*64)
    int j = tid - i * NN;

    float acc = 0.0f;
    if (j > i) {
        float dt = (tnp[0] - t0p[0]) * (1.0f / TT);
        int bi = (t0 * NN + i) * DD, bj = (t0 * NN + j) * DD;
        float2 zi = *reinterpret_cast<const float2*>(Zs + bi);
        float2 zj = *reinterpret_cast<const float2*>(Zs + bj);
        const float sp_half = 0.8862269254527580f;  // sqrt(pi)/2

        #pragma unroll 4
        for (int s = 0; s < CLEN; ++s) {
            int t = t0 + s;
            float2 vi = *reinterpret_cast<const float2*>(v0t + (t * NN + i) * DD);
            float2 vj = *reinterpret_cast<const float2*>(v0t + (t * NN + j) * DD);
            float dz0 = zi.x - zj.x, dz1 = zi.y - zj.y;
            float dv0 = vi.x - vj.x, dv1 = vi.y - vj.y;

            float a2 = fmaxf(fmaf(dv0, dv0, dv1 * dv1), 1e-12f);
            float inv_a = rsqrtf(a2);
            float a = a2 * inv_a;                    // sqrt(a2)
            float b = fmaf(dz0, dv0, dz1 * dv1);
            float u = b * inv_a;                     // a*c = b/a
            float ss = fmaf(dz0, dz0, dz1 * dz1);
            float m = fmaf(-u, u, ss);
            float ediff = erff(fmaf(a, dt, u)) - erff(u);
            acc = fmaf(__expf(beta[t] - m) * inv_a, sp_half * ediff, acc);

            zi.x = fmaf(vi.x, dt, zi.x); zi.y = fmaf(vi.y, dt, zi.y);
            zj.x = fmaf(vj.x, dt, zj.x); zj.y = fmaf(vj.y, dt, zj.y);
        }
    }

    #pragma unroll
    for (int off = 32; off > 0; off >>= 1) acc += __shfl_xor(acc, off, 64);
    __shared__ float wsum[4];
    if ((threadIdx.x & 63) == 0) wsum[threadIdx.x >> 6] = acc;
    __syncthreads();
    if (threadIdx.x == 0)
        partials[bx] = wsum[0] + wsum[1] + wsum[2] + wsum[3];
}

// ---------------------------------------------------------------------------
// K3: sum the per-block partials, subtract from out (events already added).
// ---------------------------------------------------------------------------
__global__ __launch_bounds__(256) void finalize_kernel(const float* __restrict__ partials,
                                                       float* __restrict__ out) {
    float s = 0.0f;
    for (int k = threadIdx.x; k < NPARTIAL; k += 256) s += partials[k];
    #pragma unroll
    for (int off = 32; off > 0; off >>= 1) s += __shfl_xor(s, off, 64);
    __shared__ float wsum[4];
    if ((threadIdx.x & 63) == 0) wsum[threadIdx.x >> 6] = s;
    __syncthreads();
    if (threadIdx.x == 0)
        out[0] -= (wsum[0] + wsum[1] + wsum[2] + wsum[3]);
}

// ---------------------------------------------------------------------------
// Fallback path (ws too small): original monolithic kernels, atomics into out.
// ---------------------------------------------------------------------------
__global__ void zero_out(float* out) { out[0] = 0.0f; }

__device__ __forceinline__ float2 loadV_nt(const float* __restrict__ v, int t, int n) {
    return make_float2(v[(n * DD + 0) * TT + t], v[(n * DD + 1) * TT + t]);
}

__global__ __launch_bounds__(EE) void event_kernel_fb(const float* __restrict__ data,
                                                      const float* __restrict__ z0,
                                                      const float* __restrict__ v0,
                                                      const float* __restrict__ beta,
                                                      const float* __restrict__ t0p,
                                                      const float* __restrict__ tnp,
                                                      float* __restrict__ out) {
    int e = threadIdx.x;
    float dt = (tnp[0] - t0p[0]) * (1.0f / TT);
    float tm = data[e * 3 + 2];
    int i = (int)floorf(data[e * 3 + 0]);
    int j = (int)floorf(data[e * 3 + 1]);
    float idx_f = floorf(tm / dt);
    float idx_cl = (idx_f < (float)TT) ? idx_f : (idx_f - 1.0f);
    int idx = (int)idx_cl;
    float rem = tm - idx_f * dt;

    const float2* z2 = reinterpret_cast<const float2*>(z0);
    float2 zi = z2[i], zj = z2[j];
    for (int t = 0; t < idx; ++t) {
        float2 vi = loadV_nt(v0, t, i), vj = loadV_nt(v0, t, j);
        zi.x = fmaf(vi.x, dt, zi.x); zi.y = fmaf(vi.y, dt, zi.y);
        zj.x = fmaf(vj.x, dt, zj.x); zj.y = fmaf(vj.y, dt, zj.y);
    }
    float2 vi = loadV_nt(v0, idx, i), vj = loadV_nt(v0, idx, j);
    float d0 = fmaf(vi.x, rem, zi.x) - fmaf(vj.x, rem, zj.x);
    float d1 = fmaf(vi.y, rem, zi.y) - fmaf(vj.y, rem, zj.y);
    float contrib = beta[idx] - (d0 * d0 + d1 * d1);
    #pragma unroll
    for (int off = 32; off > 0; off >>= 1) contrib += __shfl_xor(contrib, off, 64);
    if ((threadIdx.x & 63) == 0) atomicAdd(out, contrib);
}

__global__ __launch_bounds__(256) void pair_kernel_fb(const float* __restrict__ v0,
                                                      const float* __restrict__ z0,
                                                      const float* __restrict__ beta,
                                                      const float* __restrict__ t0p,
                                                      const float* __restrict__ tnp,
                                                      float* __restrict__ out) {
    int tid = blockIdx.x * 256 + threadIdx.x;
    int i = tid / NN, j = tid - i * NN;
    float acc = 0.0f;
    if (j > i) {
        float dt = (tnp[0] - t0p[0]) * (1.0f / TT);
        const float2* z2 = reinterpret_cast<const float2*>(z0);
        float2 zi = z2[i], zj = z2[j];
        const float sp_half = 0.8862269254527580f;
        for (int t = 0; t < TT; ++t) {
            float2 vi = loadV_nt(v0, t, i), vj = loadV_nt(v0, t, j);
            float dz0 = zi.x - zj.x, dz1 = zi.y - zj.y;
            float dv0 = vi.x - vj.x, dv1 = vi.y - vj.y;
            float a2 = fmaxf(fmaf(dv0, dv0, dv1 * dv1), 1e-12f);
            float inv_a = rsqrtf(a2);
            float a = a2 * inv_a;
            float b = fmaf(dz0, dv0, dz1 * dv1);
            float u = b * inv_a;
            float m = fmaf(-u, u, fmaf(dz0, dz0, dz1 * dz1));
            float ediff = erff(fmaf(a, dt, u)) - erff(u);
            acc = fmaf(__expf(beta[t] - m) * inv_a, sp_half * ediff, acc);
            zi.x = fmaf(vi.x, dt, zi.x); zi.y = fmaf(vi.y, dt, zi.y);
            zj.x = fmaf(vj.x, dt, zj.x); zj.y = fmaf(vj.y, dt, zj.y);
        }
    }
    #pragma unroll
    for (int off = 32; off > 0; off >>= 1) acc += __shfl_xor(acc, off, 64);
    if ((threadIdx.x & 63) == 0) atomicAdd(out, -acc);
}

// ---------------------------------------------------------------------------
extern "C" void kernel_launch(void* const* d_in, const int* in_sizes, int n_in,
                              void* d_out, int out_size, void* d_ws, size_t ws_size,
                              hipStream_t stream) {
    const float* data = (const float*)d_in[0];
    const float* t0p  = (const float*)d_in[1];
    const float* tnp  = (const float*)d_in[2];
    const float* z0   = (const float*)d_in[3];
    const float* v0   = (const float*)d_in[4];
    const float* beta = (const float*)d_in[5];
    float* out = (float*)d_out;
    float* ws  = (float*)d_ws;

    if (ws_size >= sizeof(float) * (size_t)WS_FLOATS) {
        prep_kernel<<<387, 256, 0, stream>>>(v0, z0, t0p, tnp, ws, out);
        pair_event_kernel<<<NPARTIAL + 1, 256, 0, stream>>>(ws, z0, beta, data, t0p, tnp,
                                                            ws + WS_PART, out);
        finalize_kernel<<<1, 256, 0, stream>>>(ws + WS_PART, out);
    } else {
        zero_out<<<1, 1, 0, stream>>>(out);
        event_kernel_fb<<<1, EE, 0, stream>>>(data, z0, v0, beta, t0p, tnp, out);
        pair_kernel_fb<<<PAIRBLOCKS, 256, 0, stream>>>(v0, z0, beta, t0p, tnp, out);
    }
}